// Round 2
// 3378.061 us; speedup vs baseline: 4.4195x; 4.4195x over previous
//
#include <hip/hip_runtime.h>
#include <hip/hip_bf16.h>
#include <math.h>

typedef __hip_bfloat16 bf16;
typedef __bf16 nbf16;
typedef __bf16 bf16x8 __attribute__((ext_vector_type(8)));
typedef __bf16 bf16x2 __attribute__((ext_vector_type(2)));
typedef float f32x4 __attribute__((ext_vector_type(4)));

#define D_MODEL 1024
#define NHEAD   16
#define HDK     64
#define BATCH   2
#define SEQ     2048

// ---------------------------------------------------------------------------
// Dtype auto-detect: sample X's first 4096 u16 words. bf16 N(0,1) data has
// exponent field in [96,141] essentially always; float32 data misread as u16
// has random mantissa halves (~59% plausible). flag=1 -> inputs are bf16.
// ---------------------------------------------------------------------------
__global__ void detect_dtype(const unsigned short* __restrict__ x, int* flag) {
    __shared__ int cnt;
    if (threadIdx.x == 0) cnt = 0;
    __syncthreads();
    int local = 0;
    for (int i = threadIdx.x; i < 4096; i += 256) {
        const unsigned short v = x[i];
        const int e = (v >> 7) & 0xFF;
        if (v == 0 || (e >= 96 && e <= 141)) local++;
    }
    atomicAdd(&cnt, local);
    __syncthreads();
    if (threadIdx.x == 0) *flag = (cnt >= 3600) ? 1 : 0;
}

__device__ __forceinline__ float ldIn(const void* p, size_t i, int isbf16) {
    return isbf16 ? __bfloat162float(((const bf16*)p)[i])
                  : ((const float*)p)[i];
}

// ---------------------------------------------------------------------------
// Scalar projection GEMM (unchanged, proven): C[m][n] = sum_k A[m][k]*W[k][n].
// ---------------------------------------------------------------------------
template<bool A_FLAG, int OUT_MODE>
__global__ void proj_scalar(const void* __restrict__ Araw,
                            const void* __restrict__ Wraw,
                            const void* __restrict__ Braw,
                            void* __restrict__ Cout,
                            const int* __restrict__ flagp) {
    const int flag = *flagp;
    const int m    = blockIdx.x;          // 0..4095
    const int tid  = threadIdx.x;         // 0..255

    float acc[4] = {0.f, 0.f, 0.f, 0.f};
    for (int k = 0; k < D_MODEL; ++k) {
        const float a = A_FLAG
            ? ldIn(Araw, (size_t)m * D_MODEL + k, flag)
            : __bfloat162float(((const bf16*)Araw)[(size_t)m * D_MODEL + k]);
        #pragma unroll
        for (int j = 0; j < 4; ++j) {
            const int n = tid + j * 256;
            acc[j] += a * ldIn(Wraw, (size_t)k * D_MODEL + n, flag);
        }
    }
    #pragma unroll
    for (int j = 0; j < 4; ++j) {
        const int n = tid + j * 256;
        const float v = acc[j] + ldIn(Braw, (size_t)n, flag);
        if (OUT_MODE == 0) {
            const int b = m >> 11, s = m & (SEQ - 1);
            const int h = n >> 6,  d = n & (HDK - 1);
            ((bf16*)Cout)[(((size_t)(b * NHEAD + h)) * SEQ + s) * HDK + d] =
                __float2bfloat16(v);
        } else {
            if (flag) ((bf16*)Cout)[(size_t)m * D_MODEL + n] = __float2bfloat16(v);
            else      ((float*)Cout)[(size_t)m * D_MODEL + n] = v;
        }
    }
}

// ---------------------------------------------------------------------------
// MFMA flash attention. Block = 256 threads = 4 waves; wave owns 16 q-rows
// (block tile 64 q-rows). KV tile = 64. Swapped QK^T: S^T = mfma(K, Q) so the
// softmax reduce axis (kv) is lane-local (16 regs) + shfl_xor 16/32.
//
// Lane/q-row bookkeeping (the round-1 bug): softmax stats (m2, alpha, lden)
// live per-lane for q = l15 (S^T column); the O accumulator's rows are
// q = lg*4 + r (C/D layout row=(lane>>4)*4+reg). Any per-q factor applied to
// o[][r] must first be shuffled from lane (lg*4+r): av[r]=__shfl(alpha,lg*4+r).
// ---------------------------------------------------------------------------
__global__ __launch_bounds__(256, 3) void attn_mfma(
        const bf16* __restrict__ qg, const bf16* __restrict__ kg,
        const bf16* __restrict__ vg, bf16* __restrict__ cg) {
    __shared__ nbf16 VT[2][64][72];   // V^T tile, padded: row stride 144B
    __shared__ nbf16 PB[4][16][72];   // per-wave P tile [q][kv]

    const int tid  = threadIdx.x;
    const int wid  = tid >> 6;
    const int lane = tid & 63;
    const int l15  = lane & 15;
    const int lg   = lane >> 4;       // 0..3

    // bijective XCD swizzle: 1024 blocks -> 128-block chunks per XCD
    const int wg = blockIdx.x;
    const int sw = (wg & 7) * 128 + (wg >> 3);
    const int bh = sw >> 5;           // 0..31  (b*16 + h)
    const int qt = sw & 31;           // q tile index

    const nbf16* qb = (const nbf16*)qg + (size_t)bh * SEQ * HDK;
    const nbf16* kb = (const nbf16*)kg + (size_t)bh * SEQ * HDK;
    const nbf16* vb = (const nbf16*)vg + (size_t)bh * SEQ * HDK;

    // Q fragments: wave's 16 q rows, B-frag of Q^T == contiguous 8 bf16 of a Q row
    const int qrow = qt * 64 + wid * 16 + l15;
    const nbf16* qp = qb + (size_t)qrow * HDK + lg * 8;
    const bf16x8 qf0 = *(const bf16x8*)qp;
    const bf16x8 qf1 = *(const bf16x8*)(qp + 32);

    // V staging map: lane covers all 64 kv (conflict-free LDS writes),
    // d-block is wave-constant.
    const int kvl = tid & 63;
    const int d00 = (tid >> 6) * 8;

    // stage tile 0
    {
        uint4 a0 = *(const uint4*)(vb + (size_t)kvl * HDK + d00);
        uint4 a1 = *(const uint4*)(vb + (size_t)kvl * HDK + d00 + 32);
        const nbf16* e0 = (const nbf16*)&a0;
        const nbf16* e1 = (const nbf16*)&a1;
        #pragma unroll
        for (int j = 0; j < 8; ++j) VT[0][d00 + j][kvl] = e0[j];
        #pragma unroll
        for (int j = 0; j < 8; ++j) VT[0][d00 + 32 + j][kvl] = e1[j];
    }

    float m2   = -3.0e38f;     // running max (log2 domain), for q = l15
    float lden = 0.f;          // running denominator, for q = l15
    const f32x4 fzero = {0.f, 0.f, 0.f, 0.f};
    f32x4 o[4];
    #pragma unroll
    for (int i = 0; i < 4; ++i) o[i] = fzero;

    const float SC = 0.125f * 1.44269504088896340736f;  // scale * log2(e)
    const int NT = SEQ / 64;   // 32

    for (int t = 0; t < NT; ++t) {
        const int cur = t & 1;
        uint4 a0, a1;
        if (t + 1 < NT) {   // prefetch next V tile into regs (hides HBM/L2 lat)
            const nbf16* vt = vb + (size_t)(t + 1) * 64 * HDK;
            a0 = *(const uint4*)(vt + (size_t)kvl * HDK + d00);
            a1 = *(const uint4*)(vt + (size_t)kvl * HDK + d00 + 32);
        }
        __syncthreads();   // VT[cur] visible; prev readers of VT[cur^1] done

        // ---- QK^T: S^T[kv][q], 4 kv-subtiles of 16 ----
        f32x4 st[4];
        const nbf16* kt = kb + (size_t)t * 64 * HDK;
        #pragma unroll
        for (int sub = 0; sub < 4; ++sub) {
            const nbf16* kp = kt + (size_t)(sub * 16 + l15) * HDK + lg * 8;
            const bf16x8 kf0 = *(const bf16x8*)kp;
            const bf16x8 kf1 = *(const bf16x8*)(kp + 32);
            f32x4 a = fzero;
            a = __builtin_amdgcn_mfma_f32_16x16x32_bf16(kf0, qf0, a, 0, 0, 0);
            a = __builtin_amdgcn_mfma_f32_16x16x32_bf16(kf1, qf1, a, 0, 0, 0);
            st[sub] = a;
        }

        // ---- online softmax: per q column (q = lane&15) ----
        float tm = -3.0e38f;
        #pragma unroll
        for (int s_ = 0; s_ < 4; ++s_) {
            #pragma unroll
            for (int r = 0; r < 4; ++r) {
                st[s_][r] *= SC;
                tm = fmaxf(tm, st[s_][r]);
            }
        }
        tm = fmaxf(tm, __shfl_xor(tm, 16, 64));
        tm = fmaxf(tm, __shfl_xor(tm, 32, 64));
        const float mnew  = fmaxf(m2, tm);
        const float alpha = exp2f(m2 - mnew);   // for q = l15
        float ts = 0.f;
        #pragma unroll
        for (int s_ = 0; s_ < 4; ++s_) {
            #pragma unroll
            for (int pi = 0; pi < 2; ++pi) {
                const float p0 = exp2f(st[s_][pi * 2]     - mnew);
                const float p1 = exp2f(st[s_][pi * 2 + 1] - mnew);
                ts += p0 + p1;
                bf16x2 pk = {(nbf16)p0, (nbf16)p1};
                *(bf16x2*)&PB[wid][l15][s_ * 16 + lg * 4 + pi * 2] = pk;
            }
        }
        ts += __shfl_xor(ts, 16, 64);
        ts += __shfl_xor(ts, 32, 64);
        lden = lden * alpha + ts;
        m2 = mnew;

        // ROUND-1 FIX: o[][r] holds q = lg*4 + r; fetch that q's alpha from
        // lane (lg*4+r) (whose l15 == lg*4+r) before rescaling.
        float av[4];
        #pragma unroll
        for (int r = 0; r < 4; ++r) av[r] = __shfl(alpha, lg * 4 + r, 64);
        #pragma unroll
        for (int i = 0; i < 4; ++i) {
            #pragma unroll
            for (int r = 0; r < 4; ++r) o[i][r] *= av[r];
        }

        // wave-local fence: P ds_writes complete before P ds_reads
        __asm__ volatile("s_waitcnt lgkmcnt(0)" ::: "memory");

        // ---- PV: O[q][d] += P · V ----
        const bf16x8 pf0 = *(const bf16x8*)&PB[wid][l15][lg * 8];
        const bf16x8 pf1 = *(const bf16x8*)&PB[wid][l15][lg * 8 + 32];
        #pragma unroll
        for (int db = 0; db < 4; ++db) {
            const bf16x8 vf0 = *(const bf16x8*)&VT[cur][db * 16 + l15][lg * 8];
            const bf16x8 vf1 = *(const bf16x8*)&VT[cur][db * 16 + l15][lg * 8 + 32];
            o[db] = __builtin_amdgcn_mfma_f32_16x16x32_bf16(pf0, vf0, o[db], 0, 0, 0);
            o[db] = __builtin_amdgcn_mfma_f32_16x16x32_bf16(pf1, vf1, o[db], 0, 0, 0);
        }

        // write prefetched V tile into the other buffer (visible after next barrier)
        if (t + 1 < NT) {
            const nbf16* e0 = (const nbf16*)&a0;
            const nbf16* e1 = (const nbf16*)&a1;
            #pragma unroll
            for (int j = 0; j < 8; ++j) VT[cur ^ 1][d00 + j][kvl] = e0[j];
            #pragma unroll
            for (int j = 0; j < 8; ++j) VT[cur ^ 1][d00 + 32 + j][kvl] = e1[j];
        }
    }

    // ---- epilogue: normalize + write concat (B,S,D) bf16 ----
    const int b = bh >> 4, h = bh & 15;
    float invd[4];
    #pragma unroll
    for (int r = 0; r < 4; ++r)
        invd[r] = 1.f / __shfl(lden, lg * 4 + r, 64);
    nbf16* cw = (nbf16*)cg;
    #pragma unroll
    for (int db = 0; db < 4; ++db) {
        #pragma unroll
        for (int r = 0; r < 4; ++r) {
            const int qr2 = qt * 64 + wid * 16 + lg * 4 + r;
            const size_t off =
                ((size_t)(b * SEQ + qr2)) * D_MODEL + h * HDK + db * 16 + l15;
            cw[off] = (nbf16)(o[db][r] * invd[r]);
        }
    }
}

// ---------------------------------------------------------------------------
extern "C" void kernel_launch(void* const* d_in, const int* in_sizes, int n_in,
                              void* d_out, int out_size, void* d_ws, size_t ws_size,
                              hipStream_t stream) {
    const void* X  = d_in[0];
    const void* Y  = d_in[1];
    const void* qW = d_in[2];
    const void* qB = d_in[3];
    const void* kW = d_in[4];
    const void* kB = d_in[5];
    const void* vW = d_in[6];
    const void* vB = d_in[7];
    const void* oW = d_in[8];
    const void* oB = d_in[9];

    bf16* ws = (bf16*)d_ws;
    const size_t QSZ = (size_t)BATCH * SEQ * D_MODEL;   // 4M elems
    bf16* qbuf = ws;                 // (B,H,S,dk)
    bf16* kbuf = qbuf + QSZ;
    bf16* vbuf = kbuf + QSZ;
    bf16* cbuf = vbuf + QSZ;         // concat (B,S,D)
    int*  flag = (int*)(cbuf + QSZ); // at byte offset 32MB

    detect_dtype<<<1, 256, 0, stream>>>((const unsigned short*)X, flag);

    const int M = BATCH * SEQ;       // 4096
    proj_scalar<true, 0><<<M, 256, 0, stream>>>(Y, qW, qB, qbuf, flag);
    proj_scalar<true, 0><<<M, 256, 0, stream>>>(X, kW, kB, kbuf, flag);
    proj_scalar<true, 0><<<M, 256, 0, stream>>>(X, vW, vB, vbuf, flag);

    attn_mfma<<<dim3(BATCH * NHEAD * (SEQ / 64)), 256, 0, stream>>>(
        qbuf, kbuf, vbuf, cbuf);

    proj_scalar<false, 1><<<M, 256, 0, stream>>>(cbuf, oW, oB, d_out, flag);
}

// Round 3
// 352.322 us; speedup vs baseline: 42.3744x; 9.5880x over previous
//
#include <hip/hip_runtime.h>
#include <hip/hip_bf16.h>
#include <math.h>

typedef __hip_bfloat16 bf16;
typedef __bf16 nbf16;
typedef __bf16 bf16x8 __attribute__((ext_vector_type(8)));
typedef __bf16 bf16x2 __attribute__((ext_vector_type(2)));
typedef float f32x4 __attribute__((ext_vector_type(4)));

#define D_MODEL 1024
#define NHEAD   16
#define HDK     64
#define BATCH   2
#define SEQ     2048

// ---------------------------------------------------------------------------
// Dtype auto-detect (unchanged, proven).
// ---------------------------------------------------------------------------
__global__ void detect_dtype(const unsigned short* __restrict__ x, int* flag) {
    __shared__ int cnt;
    if (threadIdx.x == 0) cnt = 0;
    __syncthreads();
    int local = 0;
    for (int i = threadIdx.x; i < 4096; i += 256) {
        const unsigned short v = x[i];
        const int e = (v >> 7) & 0xFF;
        if (v == 0 || (e >= 96 && e <= 141)) local++;
    }
    atomicAdd(&cnt, local);
    __syncthreads();
    if (threadIdx.x == 0) *flag = (cnt >= 3600) ? 1 : 0;
}

__device__ __forceinline__ float ldIn(const void* p, size_t i, int isbf16) {
    return isbf16 ? __bfloat162float(((const bf16*)p)[i])
                  : ((const float*)p)[i];
}

__device__ __forceinline__ void gload_lds16(const void* g, void* l) {
    __builtin_amdgcn_global_load_lds(
        (const __attribute__((address_space(1))) void*)g,
        (__attribute__((address_space(3))) void*)l, 16, 0, 0);
}

// ---------------------------------------------------------------------------
// Convert X/Y to bf16 (copy if already bf16). 8 elems/thread.
// ---------------------------------------------------------------------------
__global__ void tobf16(const void* __restrict__ in, nbf16* __restrict__ out,
                       const int* __restrict__ flagp) {
    const int flag = *flagp;
    const size_t i = ((size_t)blockIdx.x * 256 + threadIdx.x) * 8;
    if (flag) {
        *(uint4*)(out + i) = *(const uint4*)((const nbf16*)in + i);
    } else {
        const float4 a = *(const float4*)((const float*)in + i);
        const float4 b = *(const float4*)((const float*)in + i + 4);
        bf16x8 v = {(nbf16)a.x, (nbf16)a.y, (nbf16)a.z, (nbf16)a.w,
                    (nbf16)b.x, (nbf16)b.y, (nbf16)b.z, (nbf16)b.w};
        *(bf16x8*)(out + i) = v;
    }
}

// ---------------------------------------------------------------------------
// Weight transpose: W[k][n] (flag dtype) -> Wt[n][k] bf16. 64x64 LDS tile,
// +1-pad (65) so the transposed read walks consecutive banks.
// ---------------------------------------------------------------------------
__global__ void wtrans(const void* __restrict__ W, nbf16* __restrict__ Wt,
                       const int* __restrict__ flagp) {
    const int flag = *flagp;
    __shared__ float T[64][65];
    const int k0 = blockIdx.x * 64, n0 = blockIdx.y * 64;
    #pragma unroll
    for (int i = 0; i < 16; ++i) {
        const int idx = threadIdx.x + i * 256;
        const int r = idx >> 6, c = idx & 63;
        T[r][c] = ldIn(W, (size_t)(k0 + r) * D_MODEL + n0 + c, flag);
    }
    __syncthreads();
    #pragma unroll
    for (int i = 0; i < 16; ++i) {
        const int idx = threadIdx.x + i * 256;
        const int n = idx >> 6, k = idx & 63;
        Wt[(size_t)(n0 + n) * D_MODEL + k0 + k] = (nbf16)T[k][n];
    }
}

// ---------------------------------------------------------------------------
// MFMA projection GEMM: C[m][n] = sum_k A[m][k] * Wt[n][k] + bias[n].
// A: [4096][1024] bf16 row-major. Wt: [1024][1024] bf16 (n-major).
// Tile BM=128 x BN=64, BK=64. 256 thr = 4 waves (2x2); wave = 64x32 = 4x2
// frags of 16x16x32. Staging: global_load_lds w16, linear LDS dest +
// pre-XOR-swizzled global source (slot ^= row&7); ds_read applies same XOR
// -> 2-way (free) bank access. One barrier per K-step (T3 minimal).
// OUT_MODE 0: scatter bf16 to (B,H,S,dk). OUT_MODE 1: row-major, dtype=flag.
// ---------------------------------------------------------------------------
template<int OUT_MODE>
__global__ __launch_bounds__(256, 2) void proj_mfma(
        const nbf16* __restrict__ A, const nbf16* __restrict__ Wt,
        const void* __restrict__ Braw, void* __restrict__ Cout,
        const int* __restrict__ flagp) {
    __shared__ nbf16 Al[2][128][64];   // 32 KB
    __shared__ nbf16 Bl[2][64][64];    // 16 KB

    const int flag = *flagp;
    const int tid  = threadIdx.x;
    const int wid  = tid >> 6;
    const int lane = tid & 63;
    const int l15  = lane & 15;
    const int lg   = lane >> 4;
    const int wr   = wid >> 1;         // 0..1: m-half
    const int wc   = wid & 1;          // 0..1: n-half

    // bijective XCD swizzle (512 blocks, 64 per XCD chunk)
    const int id = blockIdx.x;
    const int sw = (id & 7) * 64 + (id >> 3);
    const int m0 = (sw >> 4) * 128;    // 32 m-tiles
    const int n0 = (sw & 15) * 64;     // 16 n-tiles

    // ---- staging (per K-tile t) ----
    // A: 4 wave-issues of 1KB; LDS linear [128][64]; row = i*32+wid*8+(lane>>3)
    // B: 2 wave-issues;        LDS linear [64][64]
    #define STAGE(curb, t)                                                     \
    {                                                                          \
        const int _k0 = (t) * 64;                                              \
        _Pragma("unroll")                                                      \
        for (int i = 0; i < 4; ++i) {                                          \
            const int row = i * 32 + wid * 8 + (lane >> 3);                    \
            const int ss  = (lane & 7) ^ (row & 7);                            \
            gload_lds16(A + (size_t)(m0 + row) * D_MODEL + _k0 + ss * 8,       \
                        (nbf16*)&Al[curb][0][0] + i * 2048 + wid * 512);       \
        }                                                                      \
        _Pragma("unroll")                                                      \
        for (int i = 0; i < 2; ++i) {                                          \
            const int row = i * 32 + wid * 8 + (lane >> 3);                    \
            const int ss  = (lane & 7) ^ (row & 7);                            \
            gload_lds16(Wt + (size_t)(n0 + row) * D_MODEL + _k0 + ss * 8,      \
                        (nbf16*)&Bl[curb][0][0] + i * 2048 + wid * 512);       \
        }                                                                      \
    }

    f32x4 acc[4][2];
    #pragma unroll
    for (int mi = 0; mi < 4; ++mi)
        #pragma unroll
        for (int ni = 0; ni < 2; ++ni) acc[mi][ni] = (f32x4){0.f, 0.f, 0.f, 0.f};

    STAGE(0, 0);
    __syncthreads();

    const int NT = D_MODEL / 64;   // 16
    for (int t = 0; t < NT; ++t) {
        const int cur = t & 1;
        if (t + 1 < NT) STAGE(cur ^ 1, t + 1);   // loads fly under the MFMAs

        #pragma unroll
        for (int kk = 0; kk < 2; ++kk) {         // k-halves of BK=64
            bf16x8 af[4], bfr[2];
            #pragma unroll
            for (int mi = 0; mi < 4; ++mi) {
                const int ar = wr * 64 + mi * 16 + l15;
                const int sl = ((kk << 2) + lg) ^ (ar & 7);
                af[mi] = *(const bf16x8*)((const nbf16*)&Al[cur][ar][0] + sl * 8);
            }
            #pragma unroll
            for (int ni = 0; ni < 2; ++ni) {
                const int br = wc * 32 + ni * 16 + l15;
                const int sl = ((kk << 2) + lg) ^ (br & 7);
                bfr[ni] = *(const bf16x8*)((const nbf16*)&Bl[cur][br][0] + sl * 8);
            }
            #pragma unroll
            for (int mi = 0; mi < 4; ++mi)
                #pragma unroll
                for (int ni = 0; ni < 2; ++ni)
                    acc[mi][ni] = __builtin_amdgcn_mfma_f32_16x16x32_bf16(
                        af[mi], bfr[ni], acc[mi][ni], 0, 0, 0);
        }
        __syncthreads();   // drains staging vmcnt; all reads of cur done
    }
    #undef STAGE

    // ---- epilogue: bias + store. C/D layout: col(n)=l15, row(m)=lg*4+r ----
    #pragma unroll
    for (int ni = 0; ni < 2; ++ni) {
        const int n = n0 + wc * 32 + ni * 16 + l15;
        const float bias = ldIn(Braw, (size_t)n, flag);
        #pragma unroll
        for (int mi = 0; mi < 4; ++mi) {
            #pragma unroll
            for (int r = 0; r < 4; ++r) {
                const int m = m0 + wr * 64 + mi * 16 + lg * 4 + r;
                const float v = acc[mi][ni][r] + bias;
                if (OUT_MODE == 0) {
                    const int b = m >> 11, s = m & (SEQ - 1);
                    const int h = n >> 6,  d = n & (HDK - 1);
                    ((bf16*)Cout)[(((size_t)(b * NHEAD + h)) * SEQ + s) * HDK + d] =
                        __float2bfloat16(v);
                } else {
                    if (flag) ((bf16*)Cout)[(size_t)m * D_MODEL + n] = __float2bfloat16(v);
                    else      ((float*)Cout)[(size_t)m * D_MODEL + n] = v;
                }
            }
        }
    }
}

// ---------------------------------------------------------------------------
// MFMA flash attention (unchanged, proven in round 2).
// ---------------------------------------------------------------------------
__global__ __launch_bounds__(256, 3) void attn_mfma(
        const bf16* __restrict__ qg, const bf16* __restrict__ kg,
        const bf16* __restrict__ vg, bf16* __restrict__ cg) {
    __shared__ nbf16 VT[2][64][72];
    __shared__ nbf16 PB[4][16][72];

    const int tid  = threadIdx.x;
    const int wid  = tid >> 6;
    const int lane = tid & 63;
    const int l15  = lane & 15;
    const int lg   = lane >> 4;

    const int wg = blockIdx.x;
    const int sw = (wg & 7) * 128 + (wg >> 3);
    const int bh = sw >> 5;
    const int qt = sw & 31;

    const nbf16* qb = (const nbf16*)qg + (size_t)bh * SEQ * HDK;
    const nbf16* kb = (const nbf16*)kg + (size_t)bh * SEQ * HDK;
    const nbf16* vb = (const nbf16*)vg + (size_t)bh * SEQ * HDK;

    const int qrow = qt * 64 + wid * 16 + l15;
    const nbf16* qp = qb + (size_t)qrow * HDK + lg * 8;
    const bf16x8 qf0 = *(const bf16x8*)qp;
    const bf16x8 qf1 = *(const bf16x8*)(qp + 32);

    const int kvl = tid & 63;
    const int d00 = (tid >> 6) * 8;

    {
        uint4 a0 = *(const uint4*)(vb + (size_t)kvl * HDK + d00);
        uint4 a1 = *(const uint4*)(vb + (size_t)kvl * HDK + d00 + 32);
        const nbf16* e0 = (const nbf16*)&a0;
        const nbf16* e1 = (const nbf16*)&a1;
        #pragma unroll
        for (int j = 0; j < 8; ++j) VT[0][d00 + j][kvl] = e0[j];
        #pragma unroll
        for (int j = 0; j < 8; ++j) VT[0][d00 + 32 + j][kvl] = e1[j];
    }

    float m2   = -3.0e38f;
    float lden = 0.f;
    const f32x4 fzero = {0.f, 0.f, 0.f, 0.f};
    f32x4 o[4];
    #pragma unroll
    for (int i = 0; i < 4; ++i) o[i] = fzero;

    const float SC = 0.125f * 1.44269504088896340736f;
    const int NT = SEQ / 64;

    for (int t = 0; t < NT; ++t) {
        const int cur = t & 1;
        uint4 a0, a1;
        if (t + 1 < NT) {
            const nbf16* vt = vb + (size_t)(t + 1) * 64 * HDK;
            a0 = *(const uint4*)(vt + (size_t)kvl * HDK + d00);
            a1 = *(const uint4*)(vt + (size_t)kvl * HDK + d00 + 32);
        }
        __syncthreads();

        f32x4 st[4];
        const nbf16* kt = kb + (size_t)t * 64 * HDK;
        #pragma unroll
        for (int sub = 0; sub < 4; ++sub) {
            const nbf16* kp = kt + (size_t)(sub * 16 + l15) * HDK + lg * 8;
            const bf16x8 kf0 = *(const bf16x8*)kp;
            const bf16x8 kf1 = *(const bf16x8*)(kp + 32);
            f32x4 a = fzero;
            a = __builtin_amdgcn_mfma_f32_16x16x32_bf16(kf0, qf0, a, 0, 0, 0);
            a = __builtin_amdgcn_mfma_f32_16x16x32_bf16(kf1, qf1, a, 0, 0, 0);
            st[sub] = a;
        }

        float tm = -3.0e38f;
        #pragma unroll
        for (int s_ = 0; s_ < 4; ++s_) {
            #pragma unroll
            for (int r = 0; r < 4; ++r) {
                st[s_][r] *= SC;
                tm = fmaxf(tm, st[s_][r]);
            }
        }
        tm = fmaxf(tm, __shfl_xor(tm, 16, 64));
        tm = fmaxf(tm, __shfl_xor(tm, 32, 64));
        const float mnew  = fmaxf(m2, tm);
        const float alpha = exp2f(m2 - mnew);
        float ts = 0.f;
        #pragma unroll
        for (int s_ = 0; s_ < 4; ++s_) {
            #pragma unroll
            for (int pi = 0; pi < 2; ++pi) {
                const float p0 = exp2f(st[s_][pi * 2]     - mnew);
                const float p1 = exp2f(st[s_][pi * 2 + 1] - mnew);
                ts += p0 + p1;
                bf16x2 pk = {(nbf16)p0, (nbf16)p1};
                *(bf16x2*)&PB[wid][l15][s_ * 16 + lg * 4 + pi * 2] = pk;
            }
        }
        ts += __shfl_xor(ts, 16, 64);
        ts += __shfl_xor(ts, 32, 64);
        lden = lden * alpha + ts;
        m2 = mnew;

        float av[4];
        #pragma unroll
        for (int r = 0; r < 4; ++r) av[r] = __shfl(alpha, lg * 4 + r, 64);
        #pragma unroll
        for (int i = 0; i < 4; ++i) {
            #pragma unroll
            for (int r = 0; r < 4; ++r) o[i][r] *= av[r];
        }

        __asm__ volatile("s_waitcnt lgkmcnt(0)" ::: "memory");

        const bf16x8 pf0 = *(const bf16x8*)&PB[wid][l15][lg * 8];
        const bf16x8 pf1 = *(const bf16x8*)&PB[wid][l15][lg * 8 + 32];
        #pragma unroll
        for (int db = 0; db < 4; ++db) {
            const bf16x8 vf0 = *(const bf16x8*)&VT[cur][db * 16 + l15][lg * 8];
            const bf16x8 vf1 = *(const bf16x8*)&VT[cur][db * 16 + l15][lg * 8 + 32];
            o[db] = __builtin_amdgcn_mfma_f32_16x16x32_bf16(pf0, vf0, o[db], 0, 0, 0);
            o[db] = __builtin_amdgcn_mfma_f32_16x16x32_bf16(pf1, vf1, o[db], 0, 0, 0);
        }

        if (t + 1 < NT) {
            const nbf16* e0 = (const nbf16*)&a0;
            const nbf16* e1 = (const nbf16*)&a1;
            #pragma unroll
            for (int j = 0; j < 8; ++j) VT[cur ^ 1][d00 + j][kvl] = e0[j];
            #pragma unroll
            for (int j = 0; j < 8; ++j) VT[cur ^ 1][d00 + 32 + j][kvl] = e1[j];
        }
    }

    const int b = bh >> 4, h = bh & 15;
    float invd[4];
    #pragma unroll
    for (int r = 0; r < 4; ++r)
        invd[r] = 1.f / __shfl(lden, lg * 4 + r, 64);
    nbf16* cw = (nbf16*)cg;
    #pragma unroll
    for (int db = 0; db < 4; ++db) {
        #pragma unroll
        for (int r = 0; r < 4; ++r) {
            const int qr2 = qt * 64 + wid * 16 + lg * 4 + r;
            const size_t off =
                ((size_t)(b * SEQ + qr2)) * D_MODEL + h * HDK + db * 16 + l15;
            cw[off] = (nbf16)(o[db][r] * invd[r]);
        }
    }
}

// ---------------------------------------------------------------------------
extern "C" void kernel_launch(void* const* d_in, const int* in_sizes, int n_in,
                              void* d_out, int out_size, void* d_ws, size_t ws_size,
                              hipStream_t stream) {
    const void* X  = d_in[0];
    const void* Y  = d_in[1];
    const void* qW = d_in[2];
    const void* qB = d_in[3];
    const void* kW = d_in[4];
    const void* kB = d_in[5];
    const void* vW = d_in[6];
    const void* vB = d_in[7];
    const void* oW = d_in[8];
    const void* oB = d_in[9];

    nbf16* ws = (nbf16*)d_ws;
    const size_t QSZ = (size_t)BATCH * SEQ * D_MODEL;   // 4M elems
    const size_t WSZ = (size_t)D_MODEL * D_MODEL;       // 1M elems
    nbf16* qbuf = ws;                  // (B,H,S,dk) bf16
    nbf16* kbuf = qbuf + QSZ;
    nbf16* vbuf = kbuf + QSZ;
    nbf16* cbuf = vbuf + QSZ;          // concat (B,S,D) bf16
    nbf16* Xb   = cbuf + QSZ;          // X as bf16
    nbf16* Yb   = Xb + QSZ;
    nbf16* Wtq  = Yb + QSZ;            // W^T bf16, [n][k]
    nbf16* Wtk  = Wtq + WSZ;
    nbf16* Wtv  = Wtk + WSZ;
    nbf16* Wto  = Wtv + WSZ;
    int*   flag = (int*)(Wto + WSZ);

    detect_dtype<<<1, 256, 0, stream>>>((const unsigned short*)X, flag);

    tobf16<<<(int)(QSZ / (256 * 8)), 256, 0, stream>>>(X, Xb, flag);
    tobf16<<<(int)(QSZ / (256 * 8)), 256, 0, stream>>>(Y, Yb, flag);

    const dim3 tg(16, 16);
    wtrans<<<tg, 256, 0, stream>>>(qW, Wtq, flag);
    wtrans<<<tg, 256, 0, stream>>>(kW, Wtk, flag);
    wtrans<<<tg, 256, 0, stream>>>(vW, Wtv, flag);
    wtrans<<<tg, 256, 0, stream>>>(oW, Wto, flag);

    proj_mfma<0><<<512, 256, 0, stream>>>(Yb, Wtq, qB, qbuf, flag);
    proj_mfma<0><<<512, 256, 0, stream>>>(Xb, Wtk, kB, kbuf, flag);
    proj_mfma<0><<<512, 256, 0, stream>>>(Xb, Wtv, vB, vbuf, flag);

    attn_mfma<<<dim3(BATCH * NHEAD * (SEQ / 64)), 256, 0, stream>>>(
        (const bf16*)qbuf, (const bf16*)kbuf, (const bf16*)vbuf, (bf16*)cbuf);

    proj_mfma<1><<<512, 256, 0, stream>>>(cbuf, Wto, oB, d_out, flag);
}

// Round 4
// 279.491 us; speedup vs baseline: 53.4164x; 1.2606x over previous
//
#include <hip/hip_runtime.h>
#include <hip/hip_bf16.h>
#include <math.h>

typedef __hip_bfloat16 bf16;
typedef __bf16 nbf16;
typedef __bf16 bf16x8 __attribute__((ext_vector_type(8)));
typedef __bf16 bf16x4 __attribute__((ext_vector_type(4)));
typedef float f32x4 __attribute__((ext_vector_type(4)));

#define D_MODEL 1024
#define NHEAD   16
#define HDK     64
#define BATCH   2
#define SEQ     2048
#define QSZ     ((size_t)BATCH * SEQ * D_MODEL)
#define WSZ     ((size_t)D_MODEL * D_MODEL)

// ---------------------------------------------------------------------------
// Dtype auto-detect (unchanged, proven).
// ---------------------------------------------------------------------------
__global__ void detect_dtype(const unsigned short* __restrict__ x, int* flag) {
    __shared__ int cnt;
    if (threadIdx.x == 0) cnt = 0;
    __syncthreads();
    int local = 0;
    for (int i = threadIdx.x; i < 4096; i += 256) {
        const unsigned short v = x[i];
        const int e = (v >> 7) & 0xFF;
        if (v == 0 || (e >= 96 && e <= 141)) local++;
    }
    atomicAdd(&cnt, local);
    __syncthreads();
    if (threadIdx.x == 0) *flag = (cnt >= 3600) ? 1 : 0;
}

__device__ __forceinline__ float ldIn(const void* p, size_t i, int isbf16) {
    return isbf16 ? __bfloat162float(((const bf16*)p)[i])
                  : ((const float*)p)[i];
}

__device__ __forceinline__ void gload_lds16(const void* g, void* l) {
    __builtin_amdgcn_global_load_lds(
        (const __attribute__((address_space(1))) void*)g,
        (__attribute__((address_space(3))) void*)l, 16, 0, 0);
}

// ---------------------------------------------------------------------------
// Convert X/Y to bf16 (copy if already bf16). 8 elems/thread.
// ---------------------------------------------------------------------------
__global__ void tobf16(const void* __restrict__ in, nbf16* __restrict__ out,
                       const int* __restrict__ flagp) {
    const int flag = *flagp;
    const size_t i = ((size_t)blockIdx.x * 256 + threadIdx.x) * 8;
    if (flag) {
        *(uint4*)(out + i) = *(const uint4*)((const nbf16*)in + i);
    } else {
        const float4 a = *(const float4*)((const float*)in + i);
        const float4 b = *(const float4*)((const float*)in + i + 4);
        bf16x8 v = {(nbf16)a.x, (nbf16)a.y, (nbf16)a.z, (nbf16)a.w,
                    (nbf16)b.x, (nbf16)b.y, (nbf16)b.z, (nbf16)b.w};
        *(bf16x8*)(out + i) = v;
    }
}

// ---------------------------------------------------------------------------
// Weight transpose: W[k][n] (flag dtype) -> Wt[n][k] bf16 (proven).
// ---------------------------------------------------------------------------
__global__ void wtrans(const void* __restrict__ W, nbf16* __restrict__ Wt,
                       const int* __restrict__ flagp) {
    const int flag = *flagp;
    __shared__ float T[64][65];
    const int k0 = blockIdx.x * 64, n0 = blockIdx.y * 64;
    #pragma unroll
    for (int i = 0; i < 16; ++i) {
        const int idx = threadIdx.x + i * 256;
        const int r = idx >> 6, c = idx & 63;
        T[r][c] = ldIn(W, (size_t)(k0 + r) * D_MODEL + n0 + c, flag);
    }
    __syncthreads();
    #pragma unroll
    for (int i = 0; i < 16; ++i) {
        const int idx = threadIdx.x + i * 256;
        const int n = idx >> 6, k = idx & 63;
        Wt[(size_t)(n0 + n) * D_MODEL + k0 + k] = (nbf16)T[k][n];
    }
}

// ---------------------------------------------------------------------------
// Shared GEMM staging macro: BMxBN tile, BK=64; A rows=128, B rows=64.
// LDS linear dest + pre-XOR-swizzled global source (proven round 3).
// ---------------------------------------------------------------------------
#define STAGE_AB(Albuf, Blbuf, Aptr, Bptr, t)                                  \
{                                                                              \
    const int _k0 = (t) * 64;                                                  \
    _Pragma("unroll")                                                          \
    for (int i = 0; i < 4; ++i) {                                              \
        const int row = i * 32 + wid * 8 + (lane >> 3);                        \
        const int ss  = (lane & 7) ^ (row & 7);                                \
        gload_lds16((Aptr) + (size_t)row * D_MODEL + _k0 + ss * 8,             \
                    (nbf16*)(Albuf) + i * 2048 + wid * 512);                   \
    }                                                                          \
    _Pragma("unroll")                                                          \
    for (int i = 0; i < 2; ++i) {                                              \
        const int row = i * 32 + wid * 8 + (lane >> 3);                        \
        const int ss  = (lane & 7) ^ (row & 7);                                \
        gload_lds16((Bptr) + (size_t)row * D_MODEL + _k0 + ss * 8,             \
                    (nbf16*)(Blbuf) + i * 2048 + wid * 512);                   \
    }                                                                          \
}

// ---------------------------------------------------------------------------
// Fused QKV projection: one kernel, N=3072 over concatenated Wt3 rows.
// Per-block: ng0 selects {Y,qW,qB,qbuf} / {X,kW,kB,kbuf} / {X,vW,vB,vbuf}.
// Tile 128x64, BK=64, 4 waves (2x2). Grid 1536 -> 3 blocks/CU (LDS 48KB).
// ---------------------------------------------------------------------------
__global__ __launch_bounds__(256, 2) void proj_qkv(
        const nbf16* __restrict__ Xb, const nbf16* __restrict__ Yb,
        const nbf16* __restrict__ Wt3,
        const void* __restrict__ qB, const void* __restrict__ kB,
        const void* __restrict__ vB,
        nbf16* __restrict__ outq, const int* __restrict__ flagp) {
    __shared__ nbf16 Al[2][128][64];
    __shared__ nbf16 Bl[2][64][64];

    const int flag = *flagp;
    const int tid  = threadIdx.x;
    const int wid  = tid >> 6;
    const int lane = tid & 63;
    const int l15  = lane & 15;
    const int lg   = lane >> 4;
    const int wr   = wid >> 1;
    const int wc   = wid & 1;

    const int id = blockIdx.x;                 // 1536 blocks
    const int sw = (id & 7) * 192 + (id >> 3); // bijective XCD swizzle
    const int m0  = (sw & 31) * 128;
    const int ng0 = (sw >> 5) * 64;            // 0..3008

    const nbf16* A  = (ng0 < D_MODEL) ? Yb : Xb;
    const nbf16* Bm = Wt3 + (size_t)ng0 * D_MODEL;
    const nbf16* Am = A + (size_t)m0 * D_MODEL;

    f32x4 acc[4][2];
    #pragma unroll
    for (int mi = 0; mi < 4; ++mi)
        #pragma unroll
        for (int ni = 0; ni < 2; ++ni) acc[mi][ni] = (f32x4){0.f, 0.f, 0.f, 0.f};

    STAGE_AB(&Al[0][0][0], &Bl[0][0][0], Am, Bm, 0);
    __syncthreads();

    const int NT = D_MODEL / 64;
    for (int t = 0; t < NT; ++t) {
        const int cur = t & 1;
        if (t + 1 < NT)
            STAGE_AB(&Al[cur ^ 1][0][0], &Bl[cur ^ 1][0][0], Am, Bm, t + 1);

        #pragma unroll
        for (int kk = 0; kk < 2; ++kk) {
            bf16x8 af[4], bfr[2];
            #pragma unroll
            for (int mi = 0; mi < 4; ++mi) {
                const int ar = wr * 64 + mi * 16 + l15;
                const int sl = ((kk << 2) + lg) ^ (ar & 7);
                af[mi] = *(const bf16x8*)((const nbf16*)&Al[cur][ar][0] + sl * 8);
            }
            #pragma unroll
            for (int ni = 0; ni < 2; ++ni) {
                const int br = wc * 32 + ni * 16 + l15;
                const int sl = ((kk << 2) + lg) ^ (br & 7);
                bfr[ni] = *(const bf16x8*)((const nbf16*)&Bl[cur][br][0] + sl * 8);
            }
            #pragma unroll
            for (int mi = 0; mi < 4; ++mi)
                #pragma unroll
                for (int ni = 0; ni < 2; ++ni)
                    acc[mi][ni] = __builtin_amdgcn_mfma_f32_16x16x32_bf16(
                        af[mi], bfr[ni], acc[mi][ni], 0, 0, 0);
        }
        __syncthreads();
    }

    #pragma unroll
    for (int ni = 0; ni < 2; ++ni) {
        const int n  = ng0 + wc * 32 + ni * 16 + l15;
        const int wh = n >> 10;              // 0=q 1=k 2=v
        const int nl = n & 1023;
        const void* bp = (wh == 0) ? qB : (wh == 1) ? kB : vB;
        const float bias = ldIn(bp, (size_t)nl, flag);
        nbf16* outp = outq + (size_t)wh * QSZ;
        #pragma unroll
        for (int mi = 0; mi < 4; ++mi) {
            #pragma unroll
            for (int r = 0; r < 4; ++r) {
                const int m = m0 + wr * 64 + mi * 16 + lg * 4 + r;
                const float v = acc[mi][ni][r] + bias;
                const int b = m >> 11, s = m & (SEQ - 1);
                const int h = nl >> 6,  d = nl & (HDK - 1);
                outp[(((size_t)(b * NHEAD + h)) * SEQ + s) * HDK + d] = (nbf16)v;
            }
        }
    }
}

// ---------------------------------------------------------------------------
// O projection: tile 128x64, row-major out, dtype per flag (proven round 3).
// ---------------------------------------------------------------------------
__global__ __launch_bounds__(256, 2) void proj_o(
        const nbf16* __restrict__ A, const nbf16* __restrict__ Wt,
        const void* __restrict__ Braw, void* __restrict__ Cout,
        const int* __restrict__ flagp) {
    __shared__ nbf16 Al[2][128][64];
    __shared__ nbf16 Bl[2][64][64];

    const int flag = *flagp;
    const int tid  = threadIdx.x;
    const int wid  = tid >> 6;
    const int lane = tid & 63;
    const int l15  = lane & 15;
    const int lg   = lane >> 4;
    const int wr   = wid >> 1;
    const int wc   = wid & 1;

    const int id = blockIdx.x;
    const int sw = (id & 7) * 64 + (id >> 3);
    const int m0 = (sw >> 4) * 128;
    const int n0 = (sw & 15) * 64;

    const nbf16* Am = A + (size_t)m0 * D_MODEL;
    const nbf16* Bm = Wt + (size_t)n0 * D_MODEL;

    f32x4 acc[4][2];
    #pragma unroll
    for (int mi = 0; mi < 4; ++mi)
        #pragma unroll
        for (int ni = 0; ni < 2; ++ni) acc[mi][ni] = (f32x4){0.f, 0.f, 0.f, 0.f};

    STAGE_AB(&Al[0][0][0], &Bl[0][0][0], Am, Bm, 0);
    __syncthreads();

    const int NT = D_MODEL / 64;
    for (int t = 0; t < NT; ++t) {
        const int cur = t & 1;
        if (t + 1 < NT)
            STAGE_AB(&Al[cur ^ 1][0][0], &Bl[cur ^ 1][0][0], Am, Bm, t + 1);

        #pragma unroll
        for (int kk = 0; kk < 2; ++kk) {
            bf16x8 af[4], bfr[2];
            #pragma unroll
            for (int mi = 0; mi < 4; ++mi) {
                const int ar = wr * 64 + mi * 16 + l15;
                const int sl = ((kk << 2) + lg) ^ (ar & 7);
                af[mi] = *(const bf16x8*)((const nbf16*)&Al[cur][ar][0] + sl * 8);
            }
            #pragma unroll
            for (int ni = 0; ni < 2; ++ni) {
                const int br = wc * 32 + ni * 16 + l15;
                const int sl = ((kk << 2) + lg) ^ (br & 7);
                bfr[ni] = *(const bf16x8*)((const nbf16*)&Bl[cur][br][0] + sl * 8);
            }
            #pragma unroll
            for (int mi = 0; mi < 4; ++mi)
                #pragma unroll
                for (int ni = 0; ni < 2; ++ni)
                    acc[mi][ni] = __builtin_amdgcn_mfma_f32_16x16x32_bf16(
                        af[mi], bfr[ni], acc[mi][ni], 0, 0, 0);
        }
        __syncthreads();
    }

    #pragma unroll
    for (int ni = 0; ni < 2; ++ni) {
        const int n = n0 + wc * 32 + ni * 16 + l15;
        const float bias = ldIn(Braw, (size_t)n, flag);
        #pragma unroll
        for (int mi = 0; mi < 4; ++mi) {
            #pragma unroll
            for (int r = 0; r < 4; ++r) {
                const int m = m0 + wr * 64 + mi * 16 + lg * 4 + r;
                const float v = acc[mi][ni][r] + bias;
                if (flag) ((bf16*)Cout)[(size_t)m * D_MODEL + n] = __float2bfloat16(v);
                else      ((float*)Cout)[(size_t)m * D_MODEL + n] = v;
            }
        }
    }
}

// ---------------------------------------------------------------------------
// MFMA flash attention v2. Block = 256 thr = 4 waves; wave owns 32 q (two
// 16-q frags) -> block 128 q; grid = 32 bh x 16 qt = 512. KV tile 64.
// K: global_load_lds double-buffered, XOR-swizzled [2][64][64].
// V: reg-transposed into VT[2][64][72] (b32 writes, conflict-free).
// P: per-wave PB[4][32][72], b64 writes.
// Softmax stats live at lane l15 (S^T col); O rows are q=lg*4+r -> shuffle
// alpha/lden from lane lg*4+r before applying (round-1 lesson).
// ---------------------------------------------------------------------------
__global__ __launch_bounds__(256, 2) void attn_mfma(
        const nbf16* __restrict__ qg, const nbf16* __restrict__ kg,
        const nbf16* __restrict__ vg, nbf16* __restrict__ cg) {
    __shared__ nbf16 KL[2][64][64];   // 16 KB
    __shared__ nbf16 VT[2][64][72];   // 18 KB
    __shared__ nbf16 PB[4][32][72];   // 18 KB

    const int tid  = threadIdx.x;
    const int wid  = tid >> 6;
    const int lane = tid & 63;
    const int l15  = lane & 15;
    const int lg   = lane >> 4;

    const int id = blockIdx.x;                // 512 blocks
    const int sw = (id & 7) * 64 + (id >> 3);
    const int bh = sw >> 4;                   // 0..31
    const int qt = sw & 15;                   // 0..15

    const nbf16* qb = qg + (size_t)bh * SEQ * HDK;
    const nbf16* kb = kg + (size_t)bh * SEQ * HDK;
    const nbf16* vb = vg + (size_t)bh * SEQ * HDK;

    // Q frags: wave's 32 q rows (two 16-row frags)
    const int qbase = qt * 128 + wid * 32;
    const nbf16* qpA = qb + (size_t)(qbase + l15) * HDK + lg * 8;
    const nbf16* qpB = qpA + 16 * HDK;
    const bf16x8 qfA0 = *(const bf16x8*)qpA;
    const bf16x8 qfA1 = *(const bf16x8*)(qpA + 32);
    const bf16x8 qfB0 = *(const bf16x8*)qpB;
    const bf16x8 qfB1 = *(const bf16x8*)(qpB + 32);

    // V staging map: thread = (g = tid>>5 -> d-block of 8, p2 = kv pair)
    const int g8 = (tid >> 5) * 8;
    const int p2 = (tid & 31) * 2;

    // K staging: 2 issues/wave, rows 0..63, XOR-swizzled source
    #define STAGEK(buf, t)                                                     \
    {                                                                          \
        _Pragma("unroll")                                                      \
        for (int i = 0; i < 2; ++i) {                                          \
            const int row = i * 32 + wid * 8 + (lane >> 3);                    \
            const int ss  = (lane & 7) ^ (row & 7);                            \
            gload_lds16(kb + (size_t)((t) * 64 + row) * HDK + ss * 8,          \
                        (nbf16*)&KL[buf][0][0] + i * 2048 + wid * 512);        \
        }                                                                      \
    }

    #define VLOAD(t)                                                           \
        a0 = *(const uint4*)(vb + (size_t)((t) * 64 + p2) * HDK + g8);         \
        a1 = *(const uint4*)(vb + (size_t)((t) * 64 + p2 + 1) * HDK + g8);

    #define VWRITE(buf)                                                        \
    {                                                                          \
        const unsigned short* e0 = (const unsigned short*)&a0;                 \
        const unsigned short* e1 = (const unsigned short*)&a1;                 \
        _Pragma("unroll")                                                      \
        for (int j = 0; j < 8; ++j)                                            \
            *(unsigned int*)&VT[buf][g8 + j][p2] =                             \
                (unsigned int)e0[j] | ((unsigned int)e1[j] << 16);             \
    }

    const float SC = 0.125f * 1.44269504088896340736f;

    #define SOFTMAX(st, m2, lden, o, pbrow)                                    \
    do {                                                                       \
        float tm = -3.0e38f;                                                   \
        _Pragma("unroll")                                                      \
        for (int s_ = 0; s_ < 4; ++s_)                                         \
            _Pragma("unroll")                                                  \
            for (int r = 0; r < 4; ++r) {                                      \
                st[s_][r] *= SC;                                               \
                tm = fmaxf(tm, st[s_][r]);                                     \
            }                                                                  \
        tm = fmaxf(tm, __shfl_xor(tm, 16, 64));                                \
        tm = fmaxf(tm, __shfl_xor(tm, 32, 64));                                \
        const float mnew  = fmaxf(m2, tm);                                     \
        const float alpha = exp2f(m2 - mnew);                                  \
        float ts = 0.f;                                                        \
        _Pragma("unroll")                                                      \
        for (int s_ = 0; s_ < 4; ++s_) {                                       \
            const float p0 = exp2f(st[s_][0] - mnew);                          \
            const float p1 = exp2f(st[s_][1] - mnew);                          \
            const float p2_ = exp2f(st[s_][2] - mnew);                         \
            const float p3 = exp2f(st[s_][3] - mnew);                          \
            ts += (p0 + p1) + (p2_ + p3);                                      \
            bf16x4 pk = {(nbf16)p0, (nbf16)p1, (nbf16)p2_, (nbf16)p3};         \
            *(bf16x4*)((pbrow) + s_ * 16 + lg * 4) = pk;                       \
        }                                                                      \
        ts += __shfl_xor(ts, 16, 64);                                          \
        ts += __shfl_xor(ts, 32, 64);                                          \
        lden = lden * alpha + ts;                                              \
        m2 = mnew;                                                             \
        float av[4];                                                           \
        _Pragma("unroll")                                                      \
        for (int r = 0; r < 4; ++r) av[r] = __shfl(alpha, lg * 4 + r, 64);     \
        _Pragma("unroll")                                                      \
        for (int i = 0; i < 4; ++i)                                            \
            _Pragma("unroll")                                                  \
            for (int r = 0; r < 4; ++r) o[i][r] *= av[r];                      \
    } while (0)

    float m2A = -3.0e38f, ldenA = 0.f;
    float m2B = -3.0e38f, ldenB = 0.f;
    f32x4 oA[4], oB[4];
    #pragma unroll
    for (int i = 0; i < 4; ++i) { oA[i] = (f32x4){0,0,0,0}; oB[i] = (f32x4){0,0,0,0}; }

    const int NT = SEQ / 64;   // 32

    // prologue: stage tile 0
    {
        uint4 a0, a1;
        STAGEK(0, 0);
        VLOAD(0);
        VWRITE(0);
    }
    __syncthreads();

    for (int t = 0; t < NT; ++t) {
        const int cur = t & 1;
        uint4 a0, a1;
        if (t + 1 < NT) {
            STAGEK(cur ^ 1, t + 1);   // DMA into other K buffer
            VLOAD(t + 1);             // V regs; written after PV
        }

        // ---- QK^T from KL[cur] ----
        f32x4 stA[4], stB[4];
        #pragma unroll
        for (int sub = 0; sub < 4; ++sub) {
            const int row = sub * 16 + l15;
            const int s0 = lg ^ (row & 7);
            const int s1 = (4 + lg) ^ (row & 7);
            const bf16x8 kf0 = *(const bf16x8*)((const nbf16*)&KL[cur][row][0] + s0 * 8);
            const bf16x8 kf1 = *(const bf16x8*)((const nbf16*)&KL[cur][row][0] + s1 * 8);
            f32x4 a = (f32x4){0,0,0,0};
            a = __builtin_amdgcn_mfma_f32_16x16x32_bf16(kf0, qfA0, a, 0, 0, 0);
            a = __builtin_amdgcn_mfma_f32_16x16x32_bf16(kf1, qfA1, a, 0, 0, 0);
            stA[sub] = a;
            f32x4 b = (f32x4){0,0,0,0};
            b = __builtin_amdgcn_mfma_f32_16x16x32_bf16(kf0, qfB0, b, 0, 0, 0);
            b = __builtin_amdgcn_mfma_f32_16x16x32_bf16(kf1, qfB1, b, 0, 0, 0);
            stB[sub] = b;
        }

        // ---- online softmax, both frags ----
        SOFTMAX(stA, m2A, ldenA, oA, &PB[wid][l15][0]);
        SOFTMAX(stB, m2B, ldenB, oB, &PB[wid][16 + l15][0]);

        // wave-local fence: P ds_writes complete before P ds_reads
        __asm__ volatile("s_waitcnt lgkmcnt(0)" ::: "memory");

        // ---- PV ----
        const bf16x8 pfA0 = *(const bf16x8*)&PB[wid][l15][lg * 8];
        const bf16x8 pfA1 = *(const bf16x8*)&PB[wid][l15][lg * 8 + 32];
        const bf16x8 pfB0 = *(const bf16x8*)&PB[wid][16 + l15][lg * 8];
        const bf16x8 pfB1 = *(const bf16x8*)&PB[wid][16 + l15][lg * 8 + 32];
        #pragma unroll
        for (int db = 0; db < 4; ++db) {
            const bf16x8 vf0 = *(const bf16x8*)&VT[cur][db * 16 + l15][lg * 8];
            const bf16x8 vf1 = *(const bf16x8*)&VT[cur][db * 16 + l15][lg * 8 + 32];
            oA[db] = __builtin_amdgcn_mfma_f32_16x16x32_bf16(pfA0, vf0, oA[db], 0, 0, 0);
            oA[db] = __builtin_amdgcn_mfma_f32_16x16x32_bf16(pfA1, vf1, oA[db], 0, 0, 0);
            oB[db] = __builtin_amdgcn_mfma_f32_16x16x32_bf16(pfB0, vf0, oB[db], 0, 0, 0);
            oB[db] = __builtin_amdgcn_mfma_f32_16x16x32_bf16(pfB1, vf1, oB[db], 0, 0, 0);
        }

        if (t + 1 < NT) VWRITE(cur ^ 1);
        __syncthreads();   // drains K DMA + V/P writes; tile handoff
    }

    // ---- epilogue ----
    const int b = bh >> 4, h = bh & 15;
    float invdA[4], invdB[4];
    #pragma unroll
    for (int r = 0; r < 4; ++r) {
        invdA[r] = 1.f / __shfl(ldenA, lg * 4 + r, 64);
        invdB[r] = 1.f / __shfl(ldenB, lg * 4 + r, 64);
    }
    #pragma unroll
    for (int db = 0; db < 4; ++db) {
        #pragma unroll
        for (int r = 0; r < 4; ++r) {
            const int qA = qbase + lg * 4 + r;
            cg[((size_t)(b * SEQ + qA)) * D_MODEL + h * HDK + db * 16 + l15] =
                (nbf16)(oA[db][r] * invdA[r]);
            const int qB_ = qbase + 16 + lg * 4 + r;
            cg[((size_t)(b * SEQ + qB_)) * D_MODEL + h * HDK + db * 16 + l15] =
                (nbf16)(oB[db][r] * invdB[r]);
        }
    }
    #undef STAGEK
    #undef VLOAD
    #undef VWRITE
    #undef SOFTMAX
}

// ---------------------------------------------------------------------------
extern "C" void kernel_launch(void* const* d_in, const int* in_sizes, int n_in,
                              void* d_out, int out_size, void* d_ws, size_t ws_size,
                              hipStream_t stream) {
    const void* X  = d_in[0];
    const void* Y  = d_in[1];
    const void* qW = d_in[2];
    const void* qB = d_in[3];
    const void* kW = d_in[4];
    const void* kB = d_in[5];
    const void* vW = d_in[6];
    const void* vB = d_in[7];
    const void* oW = d_in[8];
    const void* oB = d_in[9];

    nbf16* ws = (nbf16*)d_ws;
    nbf16* qbuf = ws;                  // (B,H,S,dk) bf16; k,v contiguous after
    nbf16* kbuf = qbuf + QSZ;
    nbf16* vbuf = kbuf + QSZ;
    nbf16* cbuf = vbuf + QSZ;          // concat (B,S,D) bf16
    nbf16* Xb   = cbuf + QSZ;
    nbf16* Yb   = Xb + QSZ;
    nbf16* Wt3  = Yb + QSZ;            // [3072][1024] q|k|v
    nbf16* Wto  = Wt3 + 3 * WSZ;
    int*   flag = (int*)(Wto + WSZ);

    detect_dtype<<<1, 256, 0, stream>>>((const unsigned short*)X, flag);

    tobf16<<<(int)(QSZ / (256 * 8)), 256, 0, stream>>>(X, Xb, flag);
    tobf16<<<(int)(QSZ / (256 * 8)), 256, 0, stream>>>(Y, Yb, flag);

    const dim3 tg(16, 16);
    wtrans<<<tg, 256, 0, stream>>>(qW, Wt3, flag);
    wtrans<<<tg, 256, 0, stream>>>(kW, Wt3 + WSZ, flag);
    wtrans<<<tg, 256, 0, stream>>>(vW, Wt3 + 2 * WSZ, flag);
    wtrans<<<tg, 256, 0, stream>>>(oW, Wto, flag);

    proj_qkv<<<1536, 256, 0, stream>>>(Xb, Yb, Wt3, qB, kB, vB, qbuf, flag);

    attn_mfma<<<512, 256, 0, stream>>>(qbuf, kbuf, vbuf, cbuf);

    proj_o<<<512, 256, 0, stream>>>(cbuf, Wto, oB, d_out, flag);
}

// Round 5
// 278.626 us; speedup vs baseline: 53.5823x; 1.0031x over previous
//
#include <hip/hip_runtime.h>
#include <hip/hip_bf16.h>
#include <math.h>

typedef __hip_bfloat16 bf16;
typedef __bf16 nbf16;
typedef __bf16 bf16x8 __attribute__((ext_vector_type(8)));
typedef __bf16 bf16x4 __attribute__((ext_vector_type(4)));
typedef float f32x4 __attribute__((ext_vector_type(4)));

#define D_MODEL 1024
#define NHEAD   16
#define HDK     64
#define BATCH   2
#define SEQ     2048
#define QSZ     ((size_t)BATCH * SEQ * D_MODEL)
#define WSZ     ((size_t)D_MODEL * D_MODEL)

// ---------------------------------------------------------------------------
// Dtype auto-detect (unchanged, proven).
// ---------------------------------------------------------------------------
__global__ void detect_dtype(const unsigned short* __restrict__ x, int* flag) {
    __shared__ int cnt;
    if (threadIdx.x == 0) cnt = 0;
    __syncthreads();
    int local = 0;
    for (int i = threadIdx.x; i < 4096; i += 256) {
        const unsigned short v = x[i];
        const int e = (v >> 7) & 0xFF;
        if (v == 0 || (e >= 96 && e <= 141)) local++;
    }
    atomicAdd(&cnt, local);
    __syncthreads();
    if (threadIdx.x == 0) *flag = (cnt >= 3600) ? 1 : 0;
}

__device__ __forceinline__ float ldIn(const void* p, size_t i, int isbf16) {
    return isbf16 ? __bfloat162float(((const bf16*)p)[i])
                  : ((const float*)p)[i];
}

__device__ __forceinline__ void gload_lds16(const void* g, void* l) {
    __builtin_amdgcn_global_load_lds(
        (const __attribute__((address_space(1))) void*)g,
        (__attribute__((address_space(3))) void*)l, 16, 0, 0);
}

// ---------------------------------------------------------------------------
// Convert X/Y to bf16 (copy if already bf16). 8 elems/thread.
// ---------------------------------------------------------------------------
__global__ void tobf16(const void* __restrict__ in, nbf16* __restrict__ out,
                       const int* __restrict__ flagp) {
    const int flag = *flagp;
    const size_t i = ((size_t)blockIdx.x * 256 + threadIdx.x) * 8;
    if (flag) {
        *(uint4*)(out + i) = *(const uint4*)((const nbf16*)in + i);
    } else {
        const float4 a = *(const float4*)((const float*)in + i);
        const float4 b = *(const float4*)((const float*)in + i + 4);
        bf16x8 v = {(nbf16)a.x, (nbf16)a.y, (nbf16)a.z, (nbf16)a.w,
                    (nbf16)b.x, (nbf16)b.y, (nbf16)b.z, (nbf16)b.w};
        *(bf16x8*)(out + i) = v;
    }
}

// ---------------------------------------------------------------------------
// Weight transpose: W[k][n] (flag dtype) -> Wt[n][k] bf16 (proven).
// ---------------------------------------------------------------------------
__global__ void wtrans(const void* __restrict__ W, nbf16* __restrict__ Wt,
                       const int* __restrict__ flagp) {
    const int flag = *flagp;
    __shared__ float T[64][65];
    const int k0 = blockIdx.x * 64, n0 = blockIdx.y * 64;
    #pragma unroll
    for (int i = 0; i < 16; ++i) {
        const int idx = threadIdx.x + i * 256;
        const int r = idx >> 6, c = idx & 63;
        T[r][c] = ldIn(W, (size_t)(k0 + r) * D_MODEL + n0 + c, flag);
    }
    __syncthreads();
    #pragma unroll
    for (int i = 0; i < 16; ++i) {
        const int idx = threadIdx.x + i * 256;
        const int n = idx >> 6, k = idx & 63;
        Wt[(size_t)(n0 + n) * D_MODEL + k0 + k] = (nbf16)T[k][n];
    }
}

// ---------------------------------------------------------------------------
// 128x128 GEMM staging: A and B both [128][64] per K-step. LDS linear dest +
// pre-XOR-swizzled global source (proven). 4 issues each of 4KB/wave-set.
// ---------------------------------------------------------------------------
#define STAGE128(Albuf, Blbuf, Aptr, Bptr, t)                                  \
{                                                                              \
    const int _k0 = (t) * 64;                                                  \
    _Pragma("unroll")                                                          \
    for (int i = 0; i < 4; ++i) {                                              \
        const int row = i * 32 + wid * 8 + (lane >> 3);                        \
        const int ss  = (lane & 7) ^ (row & 7);                                \
        gload_lds16((Aptr) + (size_t)row * D_MODEL + _k0 + ss * 8,             \
                    (nbf16*)(Albuf) + i * 2048 + wid * 512);                   \
        gload_lds16((Bptr) + (size_t)row * D_MODEL + _k0 + ss * 8,             \
                    (nbf16*)(Blbuf) + i * 2048 + wid * 512);                   \
    }                                                                          \
}

// Shared 128x128 MFMA K-loop body (4 waves as 2x2, wave tile 64x64 = 4x4).
#define GEMM128_LOOP(Al, Bl)                                                   \
    const int NT = D_MODEL / 64;                                               \
    for (int t = 0; t < NT; ++t) {                                             \
        const int cur = t & 1;                                                 \
        if (t + 1 < NT)                                                        \
            STAGE128(&Al[cur ^ 1][0][0], &Bl[cur ^ 1][0][0], Am, Bm, t + 1);   \
        _Pragma("unroll")                                                      \
        for (int kk = 0; kk < 2; ++kk) {                                       \
            bf16x8 af[4], bfr[4];                                              \
            _Pragma("unroll")                                                  \
            for (int mi = 0; mi < 4; ++mi) {                                   \
                const int ar = wr * 64 + mi * 16 + l15;                        \
                const int sl = ((kk << 2) + lg) ^ (ar & 7);                    \
                af[mi] = *(const bf16x8*)((const nbf16*)&Al[cur][ar][0] + sl * 8); \
            }                                                                  \
            _Pragma("unroll")                                                  \
            for (int ni = 0; ni < 4; ++ni) {                                   \
                const int br = wc * 64 + ni * 16 + l15;                        \
                const int sl = ((kk << 2) + lg) ^ (br & 7);                    \
                bfr[ni] = *(const bf16x8*)((const nbf16*)&Bl[cur][br][0] + sl * 8); \
            }                                                                  \
            _Pragma("unroll")                                                  \
            for (int mi = 0; mi < 4; ++mi)                                     \
                _Pragma("unroll")                                              \
                for (int ni = 0; ni < 4; ++ni)                                 \
                    acc[mi][ni] = __builtin_amdgcn_mfma_f32_16x16x32_bf16(     \
                        af[mi], bfr[ni], acc[mi][ni], 0, 0, 0);                \
        }                                                                      \
        __syncthreads();                                                       \
    }

// ---------------------------------------------------------------------------
// Fused QKV projection, 128x128 tile. N=3072 over concatenated Wt3 rows.
// Grid 768 = 32 m-tiles x 24 n-tiles; bijective XCD swizzle.
// ---------------------------------------------------------------------------
__global__ __launch_bounds__(256, 2) void proj_qkv(
        const nbf16* __restrict__ Xb, const nbf16* __restrict__ Yb,
        const nbf16* __restrict__ Wt3,
        const void* __restrict__ qB, const void* __restrict__ kB,
        const void* __restrict__ vB,
        nbf16* __restrict__ outq, const int* __restrict__ flagp) {
    __shared__ nbf16 Al[2][128][64];   // 32 KB
    __shared__ nbf16 Bl[2][128][64];   // 32 KB

    const int flag = *flagp;
    const int tid  = threadIdx.x;
    const int wid  = tid >> 6;
    const int lane = tid & 63;
    const int l15  = lane & 15;
    const int lg   = lane >> 4;
    const int wr   = wid >> 1;
    const int wc   = wid & 1;

    const int id = blockIdx.x;                 // 768 blocks
    const int sw = (id & 7) * 96 + (id >> 3);  // bijective (768 % 8 == 0)
    const int m0  = (sw & 31) * 128;
    const int ng0 = (sw >> 5) * 128;           // 0..2944, never spans weights

    const nbf16* A  = (ng0 < D_MODEL) ? Yb : Xb;
    const nbf16* Bm = Wt3 + (size_t)ng0 * D_MODEL;
    const nbf16* Am = A + (size_t)m0 * D_MODEL;

    f32x4 acc[4][4];
    #pragma unroll
    for (int mi = 0; mi < 4; ++mi)
        #pragma unroll
        for (int ni = 0; ni < 4; ++ni) acc[mi][ni] = (f32x4){0.f, 0.f, 0.f, 0.f};

    STAGE128(&Al[0][0][0], &Bl[0][0][0], Am, Bm, 0);
    __syncthreads();

    GEMM128_LOOP(Al, Bl)

    #pragma unroll
    for (int ni = 0; ni < 4; ++ni) {
        const int n  = ng0 + wc * 64 + ni * 16 + l15;
        const int wh = n >> 10;              // 0=q 1=k 2=v
        const int nl = n & 1023;
        const void* bp = (wh == 0) ? qB : (wh == 1) ? kB : vB;
        const float bias = ldIn(bp, (size_t)nl, flag);
        nbf16* outp = outq + (size_t)wh * QSZ;
        #pragma unroll
        for (int mi = 0; mi < 4; ++mi) {
            #pragma unroll
            for (int r = 0; r < 4; ++r) {
                const int m = m0 + wr * 64 + mi * 16 + lg * 4 + r;
                const float v = acc[mi][ni][r] + bias;
                const int b = m >> 11, s = m & (SEQ - 1);
                const int h = nl >> 6,  d = nl & (HDK - 1);
                outp[(((size_t)(b * NHEAD + h)) * SEQ + s) * HDK + d] = (nbf16)v;
            }
        }
    }
}

// ---------------------------------------------------------------------------
// O projection, 128x128 tile. Grid 256 = 32 m x 8 n.
// ---------------------------------------------------------------------------
__global__ __launch_bounds__(256, 2) void proj_o(
        const nbf16* __restrict__ A, const nbf16* __restrict__ Wt,
        const void* __restrict__ Braw, void* __restrict__ Cout,
        const int* __restrict__ flagp) {
    __shared__ nbf16 Al[2][128][64];
    __shared__ nbf16 Bl[2][128][64];

    const int flag = *flagp;
    const int tid  = threadIdx.x;
    const int wid  = tid >> 6;
    const int lane = tid & 63;
    const int l15  = lane & 15;
    const int lg   = lane >> 4;
    const int wr   = wid >> 1;
    const int wc   = wid & 1;

    const int id = blockIdx.x;                // 256 blocks
    const int sw = (id & 7) * 32 + (id >> 3);
    const int m0 = (sw >> 3) * 128;
    const int n0 = (sw & 7) * 128;

    const nbf16* Am = A + (size_t)m0 * D_MODEL;
    const nbf16* Bm = Wt + (size_t)n0 * D_MODEL;

    f32x4 acc[4][4];
    #pragma unroll
    for (int mi = 0; mi < 4; ++mi)
        #pragma unroll
        for (int ni = 0; ni < 4; ++ni) acc[mi][ni] = (f32x4){0.f, 0.f, 0.f, 0.f};

    STAGE128(&Al[0][0][0], &Bl[0][0][0], Am, Bm, 0);
    __syncthreads();

    GEMM128_LOOP(Al, Bl)

    #pragma unroll
    for (int ni = 0; ni < 4; ++ni) {
        const int n = n0 + wc * 64 + ni * 16 + l15;
        const float bias = ldIn(Braw, (size_t)n, flag);
        #pragma unroll
        for (int mi = 0; mi < 4; ++mi) {
            #pragma unroll
            for (int r = 0; r < 4; ++r) {
                const int m = m0 + wr * 64 + mi * 16 + lg * 4 + r;
                const float v = acc[mi][ni][r] + bias;
                if (flag) ((bf16*)Cout)[(size_t)m * D_MODEL + n] = __float2bfloat16(v);
                else      ((float*)Cout)[(size_t)m * D_MODEL + n] = v;
            }
        }
    }
}

// ---------------------------------------------------------------------------
// MFMA flash attention v2 + T5 setprio + T13 defer-max (THR=8, log2 domain).
// Structure proven round 4; softmax-stat/O-row lane bookkeeping per round 1.
// ---------------------------------------------------------------------------
__global__ __launch_bounds__(256, 2) void attn_mfma(
        const nbf16* __restrict__ qg, const nbf16* __restrict__ kg,
        const nbf16* __restrict__ vg, nbf16* __restrict__ cg) {
    __shared__ nbf16 KL[2][64][64];   // 16 KB
    __shared__ nbf16 VT[2][64][72];   // 18 KB
    __shared__ nbf16 PB[4][32][72];   // 18 KB

    const int tid  = threadIdx.x;
    const int wid  = tid >> 6;
    const int lane = tid & 63;
    const int l15  = lane & 15;
    const int lg   = lane >> 4;

    const int id = blockIdx.x;                // 512 blocks
    const int sw = (id & 7) * 64 + (id >> 3);
    const int bh = sw >> 4;                   // 0..31
    const int qt = sw & 15;                   // 0..15

    const nbf16* qb = qg + (size_t)bh * SEQ * HDK;
    const nbf16* kb = kg + (size_t)bh * SEQ * HDK;
    const nbf16* vb = vg + (size_t)bh * SEQ * HDK;

    const int qbase = qt * 128 + wid * 32;
    const nbf16* qpA = qb + (size_t)(qbase + l15) * HDK + lg * 8;
    const nbf16* qpB = qpA + 16 * HDK;
    const bf16x8 qfA0 = *(const bf16x8*)qpA;
    const bf16x8 qfA1 = *(const bf16x8*)(qpA + 32);
    const bf16x8 qfB0 = *(const bf16x8*)qpB;
    const bf16x8 qfB1 = *(const bf16x8*)(qpB + 32);

    const int g8 = (tid >> 5) * 8;
    const int p2 = (tid & 31) * 2;

    #define STAGEK(buf, t)                                                     \
    {                                                                          \
        _Pragma("unroll")                                                      \
        for (int i = 0; i < 2; ++i) {                                          \
            const int row = i * 32 + wid * 8 + (lane >> 3);                    \
            const int ss  = (lane & 7) ^ (row & 7);                            \
            gload_lds16(kb + (size_t)((t) * 64 + row) * HDK + ss * 8,          \
                        (nbf16*)&KL[buf][0][0] + i * 2048 + wid * 512);        \
        }                                                                      \
    }

    #define VLOAD(t)                                                           \
        a0 = *(const uint4*)(vb + (size_t)((t) * 64 + p2) * HDK + g8);         \
        a1 = *(const uint4*)(vb + (size_t)((t) * 64 + p2 + 1) * HDK + g8);

    #define VWRITE(buf)                                                        \
    {                                                                          \
        const unsigned short* e0 = (const unsigned short*)&a0;                 \
        const unsigned short* e1 = (const unsigned short*)&a1;                 \
        _Pragma("unroll")                                                      \
        for (int j = 0; j < 8; ++j)                                            \
            *(unsigned int*)&VT[buf][g8 + j][p2] =                             \
                (unsigned int)e0[j] | ((unsigned int)e1[j] << 16);             \
    }

    const float SC = 0.125f * 1.44269504088896340736f;

    // T13 defer-max: if no q-col's tile-max exceeds m2+8 (wave-uniform test),
    // keep old m2 (P bounded by 2^8, bf16-safe) and skip the O-rescale pass.
    #define SOFTMAX(st, m2, lden, o, pbrow)                                    \
    do {                                                                       \
        float tm = -3.0e38f;                                                   \
        _Pragma("unroll")                                                      \
        for (int s_ = 0; s_ < 4; ++s_)                                         \
            _Pragma("unroll")                                                  \
            for (int r = 0; r < 4; ++r) {                                      \
                st[s_][r] *= SC;                                               \
                tm = fmaxf(tm, st[s_][r]);                                     \
            }                                                                  \
        tm = fmaxf(tm, __shfl_xor(tm, 16, 64));                                \
        tm = fmaxf(tm, __shfl_xor(tm, 32, 64));                                \
        const bool nresc = __all(tm - m2 <= 8.0f);                             \
        const float mref = nresc ? m2 : fmaxf(m2, tm);                         \
        float ts = 0.f;                                                        \
        _Pragma("unroll")                                                      \
        for (int s_ = 0; s_ < 4; ++s_) {                                       \
            const float p0 = exp2f(st[s_][0] - mref);                          \
            const float p1 = exp2f(st[s_][1] - mref);                          \
            const float p2_ = exp2f(st[s_][2] - mref);                         \
            const float p3 = exp2f(st[s_][3] - mref);                          \
            ts += (p0 + p1) + (p2_ + p3);                                      \
            bf16x4 pk = {(nbf16)p0, (nbf16)p1, (nbf16)p2_, (nbf16)p3};         \
            *(bf16x4*)((pbrow) + s_ * 16 + lg * 4) = pk;                       \
        }                                                                      \
        ts += __shfl_xor(ts, 16, 64);                                          \
        ts += __shfl_xor(ts, 32, 64);                                          \
        if (nresc) {                                                           \
            lden += ts;                                                        \
        } else {                                                               \
            const float alpha = exp2f(m2 - mref);                              \
            lden = lden * alpha + ts;                                          \
            m2 = mref;                                                         \
            float av[4];                                                       \
            _Pragma("unroll")                                                  \
            for (int r = 0; r < 4; ++r) av[r] = __shfl(alpha, lg * 4 + r, 64); \
            _Pragma("unroll")                                                  \
            for (int i = 0; i < 4; ++i)                                        \
                _Pragma("unroll")                                              \
                for (int r = 0; r < 4; ++r) o[i][r] *= av[r];                  \
        }                                                                      \
    } while (0)

    float m2A = -3.0e38f, ldenA = 0.f;
    float m2B = -3.0e38f, ldenB = 0.f;
    f32x4 oA[4], oB[4];
    #pragma unroll
    for (int i = 0; i < 4; ++i) { oA[i] = (f32x4){0,0,0,0}; oB[i] = (f32x4){0,0,0,0}; }

    const int NT = SEQ / 64;   // 32

    {
        uint4 a0, a1;
        STAGEK(0, 0);
        VLOAD(0);
        VWRITE(0);
    }
    __syncthreads();

    for (int t = 0; t < NT; ++t) {
        const int cur = t & 1;
        uint4 a0, a1;
        if (t + 1 < NT) {
            STAGEK(cur ^ 1, t + 1);
            VLOAD(t + 1);
        }

        // ---- QK^T from KL[cur] ----
        f32x4 stA[4], stB[4];
        __builtin_amdgcn_s_setprio(1);
        #pragma unroll
        for (int sub = 0; sub < 4; ++sub) {
            const int row = sub * 16 + l15;
            const int s0 = lg ^ (row & 7);
            const int s1 = (4 + lg) ^ (row & 7);
            const bf16x8 kf0 = *(const bf16x8*)((const nbf16*)&KL[cur][row][0] + s0 * 8);
            const bf16x8 kf1 = *(const bf16x8*)((const nbf16*)&KL[cur][row][0] + s1 * 8);
            f32x4 a = (f32x4){0,0,0,0};
            a = __builtin_amdgcn_mfma_f32_16x16x32_bf16(kf0, qfA0, a, 0, 0, 0);
            a = __builtin_amdgcn_mfma_f32_16x16x32_bf16(kf1, qfA1, a, 0, 0, 0);
            stA[sub] = a;
            f32x4 b = (f32x4){0,0,0,0};
            b = __builtin_amdgcn_mfma_f32_16x16x32_bf16(kf0, qfB0, b, 0, 0, 0);
            b = __builtin_amdgcn_mfma_f32_16x16x32_bf16(kf1, qfB1, b, 0, 0, 0);
            stB[sub] = b;
        }
        __builtin_amdgcn_s_setprio(0);

        SOFTMAX(stA, m2A, ldenA, oA, &PB[wid][l15][0]);
        SOFTMAX(stB, m2B, ldenB, oB, &PB[wid][16 + l15][0]);

        __asm__ volatile("s_waitcnt lgkmcnt(0)" ::: "memory");

        // ---- PV ----
        const bf16x8 pfA0 = *(const bf16x8*)&PB[wid][l15][lg * 8];
        const bf16x8 pfA1 = *(const bf16x8*)&PB[wid][l15][lg * 8 + 32];
        const bf16x8 pfB0 = *(const bf16x8*)&PB[wid][16 + l15][lg * 8];
        const bf16x8 pfB1 = *(const bf16x8*)&PB[wid][16 + l15][lg * 8 + 32];
        __builtin_amdgcn_s_setprio(1);
        #pragma unroll
        for (int db = 0; db < 4; ++db) {
            const bf16x8 vf0 = *(const bf16x8*)&VT[cur][db * 16 + l15][lg * 8];
            const bf16x8 vf1 = *(const bf16x8*)&VT[cur][db * 16 + l15][lg * 8 + 32];
            oA[db] = __builtin_amdgcn_mfma_f32_16x16x32_bf16(pfA0, vf0, oA[db], 0, 0, 0);
            oA[db] = __builtin_amdgcn_mfma_f32_16x16x32_bf16(pfA1, vf1, oA[db], 0, 0, 0);
            oB[db] = __builtin_amdgcn_mfma_f32_16x16x32_bf16(pfB0, vf0, oB[db], 0, 0, 0);
            oB[db] = __builtin_amdgcn_mfma_f32_16x16x32_bf16(pfB1, vf1, oB[db], 0, 0, 0);
        }
        __builtin_amdgcn_s_setprio(0);

        if (t + 1 < NT) VWRITE(cur ^ 1);
        __syncthreads();
    }

    // ---- epilogue ----
    const int b = bh >> 4, h = bh & 15;
    float invdA[4], invdB[4];
    #pragma unroll
    for (int r = 0; r < 4; ++r) {
        invdA[r] = 1.f / __shfl(ldenA, lg * 4 + r, 64);
        invdB[r] = 1.f / __shfl(ldenB, lg * 4 + r, 64);
    }
    #pragma unroll
    for (int db = 0; db < 4; ++db) {
        #pragma unroll
        for (int r = 0; r < 4; ++r) {
            const int qA = qbase + lg * 4 + r;
            cg[((size_t)(b * SEQ + qA)) * D_MODEL + h * HDK + db * 16 + l15] =
                (nbf16)(oA[db][r] * invdA[r]);
            const int qB_ = qbase + 16 + lg * 4 + r;
            cg[((size_t)(b * SEQ + qB_)) * D_MODEL + h * HDK + db * 16 + l15] =
                (nbf16)(oB[db][r] * invdB[r]);
        }
    }
    #undef STAGEK
    #undef VLOAD
    #undef VWRITE
    #undef SOFTMAX
}

// ---------------------------------------------------------------------------
extern "C" void kernel_launch(void* const* d_in, const int* in_sizes, int n_in,
                              void* d_out, int out_size, void* d_ws, size_t ws_size,
                              hipStream_t stream) {
    const void* X  = d_in[0];
    const void* Y  = d_in[1];
    const void* qW = d_in[2];
    const void* qB = d_in[3];
    const void* kW = d_in[4];
    const void* kB = d_in[5];
    const void* vW = d_in[6];
    const void* vB = d_in[7];
    const void* oW = d_in[8];
    const void* oB = d_in[9];

    nbf16* ws = (nbf16*)d_ws;
    nbf16* qbuf = ws;                  // (B,H,S,dk) bf16; k,v contiguous after
    nbf16* kbuf = qbuf + QSZ;
    nbf16* vbuf = kbuf + QSZ;
    nbf16* cbuf = vbuf + QSZ;          // concat (B,S,D) bf16
    nbf16* Xb   = cbuf + QSZ;
    nbf16* Yb   = Xb + QSZ;
    nbf16* Wt3  = Yb + QSZ;            // [3072][1024] q|k|v
    nbf16* Wto  = Wt3 + 3 * WSZ;
    int*   flag = (int*)(Wto + WSZ);

    detect_dtype<<<1, 256, 0, stream>>>((const unsigned short*)X, flag);

    tobf16<<<(int)(QSZ / (256 * 8)), 256, 0, stream>>>(X, Xb, flag);
    tobf16<<<(int)(QSZ / (256 * 8)), 256, 0, stream>>>(Y, Yb, flag);

    const dim3 tg(16, 16);
    wtrans<<<tg, 256, 0, stream>>>(qW, Wt3, flag);
    wtrans<<<tg, 256, 0, stream>>>(kW, Wt3 + WSZ, flag);
    wtrans<<<tg, 256, 0, stream>>>(vW, Wt3 + 2 * WSZ, flag);
    wtrans<<<tg, 256, 0, stream>>>(oW, Wto, flag);

    proj_qkv<<<768, 256, 0, stream>>>(Xb, Yb, Wt3, qB, kB, vB, qbuf, flag);

    attn_mfma<<<512, 256, 0, stream>>>(qbuf, kbuf, vbuf, cbuf);

    proj_o<<<256, 256, 0, stream>>>(cbuf, Wto, oB, d_out, flag);
}